// Round 16
// baseline (372.766 us; speedup 1.0000x reference)
//
#include <hip/hip_runtime.h>

#define PBLK 256

typedef __attribute__((ext_vector_type(8))) short bf16x8;
typedef __attribute__((ext_vector_type(16))) float f32x16;

__device__ __forceinline__ unsigned short f2bf(float x) {
    unsigned int u = __builtin_bit_cast(unsigned int, x);
    u += 0x7fffu + ((u >> 16) & 1u);
    return (unsigned short)(u >> 16);
}

// ---- pre-pass 1: node_reps fp32 -> bf16 ----
__global__ void conv_node(const float* __restrict__ x, unsigned short* __restrict__ o, int n4) {
    int tid = blockIdx.x * PBLK + threadIdx.x;
    if (tid >= n4) return;
    const float4 v = reinterpret_cast<const float4*>(x)[tid];
    ushort4 r;
    r.x = f2bf(v.x); r.y = f2bf(v.y); r.z = f2bf(v.z); r.w = f2bf(v.w);
    reinterpret_cast<ushort4*>(o)[tid] = r;
}

// ---- pre-pass 2: pack w1 (K x 128) into SINGLE-copy 32x32x16 B-frag layout ----
template<int K>
__global__ void pack_w1(const float* __restrict__ w1, unsigned short* __restrict__ o) {
    constexpr int KS = K / 16;
    int tid = blockIdx.x * PBLK + threadIdx.x;
    if (tid >= K * 128) return;
    const int j = tid & 7;
    const int l = (tid >> 3) & 63;
    const int cts = tid >> 9;
    const int s  = cts % KS;
    const int ct = cts / KS;
    const int col = ct * 32 + (l & 31);
    const int k = s * 16 + (l >> 5) * 8 + j;
    o[tid] = f2bf(w1[(size_t)k * 128 + col]);
}

// ---- pre-pass 3: pack all w2 (128 x DOUT) into 32x32x16 B-frag layout ----
__global__ void pack_w2_all(const float* __restrict__ wa, const float* __restrict__ wb,
                            const float* __restrict__ wg, const float* __restrict__ wp,
                            const float* __restrict__ wi,
                            unsigned short* __restrict__ oa, unsigned short* __restrict__ ob,
                            unsigned short* __restrict__ og, unsigned short* __restrict__ op,
                            unsigned short* __restrict__ oi) {
    int tid = blockIdx.x * PBLK + threadIdx.x;
    if (tid >= 5 * 4096) return;
    const int term = tid >> 12, e = tid & 4095;
    const float* w; unsigned short* o; int dout;
    switch (term) {
        case 0: w = wa; o = oa; dout = 2; break;
        case 1: w = wb; o = ob; dout = 2; break;
        case 2: w = wg; o = og; dout = 2; break;
        case 3: w = wp; o = op; dout = 6; break;
        default: w = wi; o = oi; dout = 6; break;
    }
    const int j = e & 7, l = (e >> 3) & 63, s = e >> 9;
    const int col = l & 31;
    const int k = s * 16 + (l >> 5) * 8 + j;
    o[e] = (col < dout) ? f2bf(w[k * dout + col]) : (unsigned short)0;
}

// ---- async global->LDS, 16B per lane ----
__device__ __forceinline__ void gld_lds16(const unsigned short* g, unsigned char* l) {
    typedef __attribute__((address_space(1))) unsigned int GU;
    typedef __attribute__((address_space(3))) unsigned int LU;
    __builtin_amdgcn_global_load_lds((GU*)g, (LU*)l, 16, 0, 0);
}

// forced-wide 16B global load (asm "=v": value live issue->use; asm-volatile
// mutual order preserved -> countable vmcnt ledger)
template<int OFF>
__device__ __forceinline__ void glb16(bf16x8& d, const unsigned short* p) {
    if constexpr (OFF == 0)
        asm volatile("global_load_dwordx4 %0, %1, off" : "=v"(d) : "v"(p));
    else
        asm volatile("global_load_dwordx4 %0, %1, off offset:%2" : "=v"(d) : "v"(p), "i"(OFF));
}

template<int N> __device__ __forceinline__ void waitvm() {
    if constexpr (N == 0)       asm volatile("s_waitcnt vmcnt(0)"  ::: "memory");
    else if constexpr (N == 1)  asm volatile("s_waitcnt vmcnt(1)"  ::: "memory");
    else if constexpr (N == 2)  asm volatile("s_waitcnt vmcnt(2)"  ::: "memory");
    else if constexpr (N == 3)  asm volatile("s_waitcnt vmcnt(3)"  ::: "memory");
    else if constexpr (N == 4)  asm volatile("s_waitcnt vmcnt(4)"  ::: "memory");
    else if constexpr (N == 6)  asm volatile("s_waitcnt vmcnt(6)"  ::: "memory");
    else if constexpr (N == 8)  asm volatile("s_waitcnt vmcnt(8)"  ::: "memory");
    else if constexpr (N == 9)  asm volatile("s_waitcnt vmcnt(9)"  ::: "memory");
    else if constexpr (N == 12) asm volatile("s_waitcnt vmcnt(12)" ::: "memory");
    else                        asm volatile("s_waitcnt vmcnt(0)"  ::: "memory");
}

// ---- per-term config ----
template<int TERM> struct TC;
template<> struct TC<0> { static constexpr int NA = 1, NP = 1, DO = 2;
                          static constexpr int P[1][4] = {{0,0,0,0}}; };
template<> struct TC<1> { static constexpr int NA = 2, NP = 2, DO = 2;
                          static constexpr int P[2][4] = {{0,1,0,0},{1,0,0,0}}; };
template<> struct TC<2> { static constexpr int NA = 3, NP = 2, DO = 2;
                          static constexpr int P[2][4] = {{0,1,2,0},{2,1,0,0}}; };
template<> struct TC<3> { static constexpr int NA = 4, NP = 2, DO = 6;
                          static constexpr int P[2][4] = {{0,1,2,3},{3,2,1,0}}; };
template<> struct TC<4> { static constexpr int NA = 4, NP = 3, DO = 6;
                          static constexpr int P[3][4] = {{0,1,2,3},{2,1,3,0},{3,1,0,2}}; };

// ---- main term kernel ----
// Persistent grid-stride over 32-row tiles, 256 threads = 4 waves (ct 0..3),
// wave tile 32 rows x 32 cols, mfma_f32_32x32x16_bf16, r12 streaming-B
// k-loop (pure asm-load vmcnt ledger, proven).
// SINGLE X buffer (NA*8KB) -> 3-4 blocks/CU (was 2 with double-buffer).
// Gather overlap via the h-slot trick: h lives in slot NA-1 only, so after
// barrier A the next tile's gather for slots 0..NA-2 is issued immediately
// (hidden under h-write + layer-2); slot NA-1's gather is issued after
// barrier D (all waves' layer-2 reads done), drained before barrier C.
template<int TERM, int MINW>
__global__ __launch_bounds__(256, MINW) void term_mfma(
    const unsigned short* __restrict__ nodeb,  // (N,128) bf16
    const int* __restrict__ idx,               // (nrows,NA) or nullptr
    const unsigned short* __restrict__ pack,   // K*128 bf16 (single copy)
    const unsigned short* __restrict__ pk2,    // 8*64*8 bf16 packed w2
    const float* __restrict__ b1,              // (128)
    const float* __restrict__ b2,              // (DOUT)
    float* __restrict__ out,                   // (nrows,DOUT)
    int nrows, int ntiles)
{
    constexpr int NA   = TC<TERM>::NA;
    constexpr int NP   = TC<TERM>::NP;
    constexpr int DOUT = TC<TERM>::DO;
    constexpr int BUF  = NA * 8192;            // single buffer: 32 rows x 256B/slot
    __shared__ __align__(16) unsigned char lds[BUF];

    const int t    = threadIdx.x;
    const int l    = t & 63;
    const int w    = t >> 6;                   // wave id = col tile
    const int l31  = l & 31;
    const int hi   = l >> 5;
    const int l15  = l & 15;
    const int qr   = l >> 4;
    const int rowb = l31;
    const int GS   = gridDim.x;
    unsigned char* hb = lds + (NA - 1) * 8192; // h slot (= last X slot)

    // static B base pointers: block b, k-half h
    const unsigned short* pbp[NA][2];
    #pragma unroll
    for (int b = 0; b < NA; ++b)
        #pragma unroll
        for (int h = 0; h < 2; ++h)
            pbp[b][h] = pack + (((size_t)w * (NA * 8) + b * 8 + h * 4) * 64 + l) * 8;

    const int col = w * 32 + l31;
    const float bv = b1[col];
    const float b2v = (l31 < DOUT) ? b2[l31] * (float)NP : 0.0f;

    int nrw[NA * 2];
    int tile = blockIdx.x;

    // ---- prologue: gather tile0 (all slots) ----
    #pragma unroll
    for (int a = 0; a < NA; ++a)
        #pragma unroll
        for (int q = 0; q < 2; ++q) {
            const int rl = w * 8 + q * 4 + qr;
            int gr = tile * 32 + rl; if (gr >= nrows) gr = nrows - 1;
            nrw[a * 2 + q] = idx ? idx[gr * NA + a] : gr;
        }
    #pragma unroll
    for (int a = 0; a < NA; ++a)
        #pragma unroll
        for (int q = 0; q < 2; ++q) {
            const int rl = w * 8 + q * 4 + qr;
            gld_lds16(nodeb + (size_t)nrw[a * 2 + q] * 128 + ((l15 ^ (rl & 15)) << 3),
                      lds + a * 8192 + (w * 8 + q * 4) * 256);
        }
    waitvm<0>();
    __builtin_amdgcn_s_barrier();

    for (; tile < ntiles; tile += GS) {
        const bool hasnext = (tile + GS) < ntiles;

        if (hasnext) {                         // next tile's gather indices
            #pragma unroll
            for (int a = 0; a < NA; ++a)
                #pragma unroll
                for (int q = 0; q < 2; ++q) {
                    const int rl = w * 8 + q * 4 + qr;
                    int gr = (tile + GS) * 32 + rl; if (gr >= nrows) gr = nrows - 1;
                    nrw[a * 2 + q] = idx ? idx[gr * NA + a] : gr;
                }
        }

        f32x16 acc[NP];
        #pragma unroll
        for (int p = 0; p < NP; ++p)
            #pragma unroll
            for (int i = 0; i < 16; ++i) acc[p][i] = bv;

        // ---- r12 streaming-B k-loop (pure asm-load ledger) ----
        bf16x8 Bf[4][NA];
#define ISSUEB(J) do { _Pragma("unroll")                                           \
        for (int b = 0; b < NA; ++b)                                               \
            glb16<((J) & 3) * 1024>(Bf[(J) & 3][b], pbp[b][(J) >> 2]); } while (0)
#define KSTEP(C) do {                                                              \
        waitvm<NA * (((7 - (C)) < 3) ? (7 - (C)) : 3)>();                          \
        __builtin_amdgcn_sched_barrier(0);                                         \
        bf16x8 av[NA];                                                             \
        _Pragma("unroll")                                                          \
        for (int s = 0; s < NA; ++s)                                               \
            av[s] = *reinterpret_cast<const bf16x8*>(                              \
                lds + s * 8192 + rowb * 256 + ((((C) * 2 + hi) ^ (rowb & 15)) << 4)); \
        _Pragma("unroll")                                                          \
        for (int b = 0; b < NA; ++b) {                                             \
            _Pragma("unroll")                                                      \
            for (int p = 0; p < NP; ++p)                                           \
                acc[p] = __builtin_amdgcn_mfma_f32_32x32x16_bf16(                  \
                    av[TC<TERM>::P[p][b]], Bf[(C) & 3][b], acc[p], 0, 0, 0);       \
        }                                                                          \
        if constexpr ((C) + 4 <= 7) ISSUEB((C) + 4);                               \
    } while (0)
        ISSUEB(0); ISSUEB(1); ISSUEB(2); ISSUEB(3);
        KSTEP(0); KSTEP(1); KSTEP(2); KSTEP(3);
        KSTEP(4); KSTEP(5); KSTEP(6); KSTEP(7);
#undef KSTEP
#undef ISSUEB

        __builtin_amdgcn_s_barrier();          // A: all waves done reading X

        // ---- G-early: next tile's gather for slots 0..NA-2 (h untouched) ----
        if (hasnext) {
            #pragma unroll
            for (int a = 0; a < NA - 1; ++a)
                #pragma unroll
                for (int q = 0; q < 2; ++q) {
                    const int rl = w * 8 + q * 4 + qr;
                    gld_lds16(nodeb + (size_t)nrw[a * 2 + q] * 128 + ((l15 ^ (rl & 15)) << 3),
                              lds + a * 8192 + (w * 8 + q * 4) * 256);
                }
        }

        // ---- h = sum_p relu(acc_p) -> bf16 in slot NA-1, A-frag layout ----
        #pragma unroll
        for (int i = 0; i < 16; ++i) {
            const int rowl = (i & 3) + 8 * (i >> 2) + 4 * hi;
            float v = 0.0f;
            #pragma unroll
            for (int p = 0; p < NP; ++p) v += fmaxf(acc[p][i], 0.0f);
            *reinterpret_cast<unsigned short*>(
                hb + rowl * 256 + (((col >> 3) ^ (rowl & 15)) << 4) + (col & 7) * 2) = f2bf(v);
        }
        asm volatile("s_waitcnt lgkmcnt(0)" ::: "memory");
        __builtin_amdgcn_s_barrier();          // B: h visible (G-early in flight)

        // ---- layer 2: y = h @ w2 via 8 MFMAs (all waves compute, w0 stores) ----
        {
            f32x16 a2;
            #pragma unroll
            for (int i = 0; i < 16; ++i) a2[i] = 0.0f;
            #pragma unroll
            for (int s = 0; s < 8; ++s) {
                const bf16x8 ah = *reinterpret_cast<const bf16x8*>(
                    hb + rowb * 256 + (((s * 2 + hi) ^ (rowb & 15)) << 4));
                const bf16x8 bw = *reinterpret_cast<const bf16x8*>(pk2 + ((size_t)s * 64 + l) * 8);
                a2 = __builtin_amdgcn_mfma_f32_32x32x16_bf16(ah, bw, a2, 0, 0, 0);
            }
            if (w == 0 && l31 < DOUT) {
                #pragma unroll
                for (int i = 0; i < 16; ++i) {
                    const int rowl = (i & 3) + 8 * (i >> 2) + 4 * hi;
                    const int grow = tile * 32 + rowl;
                    if (grow < nrows) out[(size_t)grow * DOUT + l31] = a2[i] + b2v;
                }
            }
        }
        asm volatile("s_waitcnt lgkmcnt(0)" ::: "memory");   // this wave's h-reads done
        __builtin_amdgcn_s_barrier();          // D: ALL waves' layer-2 reads done

        // ---- G-late: slot NA-1 gather (h slot now dead) ----
        if (hasnext) {
            #pragma unroll
            for (int q = 0; q < 2; ++q) {
                const int rl = w * 8 + q * 4 + qr;
                gld_lds16(nodeb + (size_t)nrw[(NA - 1) * 2 + q] * 128 + ((l15 ^ (rl & 15)) << 3),
                          lds + (NA - 1) * 8192 + (w * 8 + q * 4) * 256);
            }
        }
        __builtin_amdgcn_sched_barrier(0);
        waitvm<0>();                           // all G (+ pk2/stores) drained
        __builtin_amdgcn_s_barrier();          // C: X ready for all waves
    }
}

extern "C" void kernel_launch(void* const* d_in, const int* in_sizes, int n_in,
                              void* d_out, int out_size, void* d_ws, size_t ws_size,
                              hipStream_t stream) {
    const float* node = (const float*)d_in[0];
    const int* bidx = (const int*)d_in[1];
    const int* gidx = (const int*)d_in[2];
    const int* pidx = (const int*)d_in[3];
    const int* iidx = (const int*)d_in[4];

    const float* aw1 = (const float*)d_in[5];
    const float* ab1 = (const float*)d_in[6];
    const float* aw2 = (const float*)d_in[7];
    const float* ab2 = (const float*)d_in[8];
    const float* bw1 = (const float*)d_in[9];
    const float* bb1 = (const float*)d_in[10];
    const float* bw2 = (const float*)d_in[11];
    const float* bb2 = (const float*)d_in[12];
    const float* gw1 = (const float*)d_in[13];
    const float* gb1 = (const float*)d_in[14];
    const float* gw2 = (const float*)d_in[15];
    const float* gb2 = (const float*)d_in[16];
    const float* pw1 = (const float*)d_in[17];
    const float* pb1 = (const float*)d_in[18];
    const float* pw2 = (const float*)d_in[19];
    const float* pb2 = (const float*)d_in[20];
    const float* iw1 = (const float*)d_in[21];
    const float* ib1 = (const float*)d_in[22];
    const float* iw2 = (const float*)d_in[23];
    const float* ib2 = (const float*)d_in[24];

    const int N   = in_sizes[0] / 128;
    const int NB  = in_sizes[1] / 2;
    const int NAg = in_sizes[2] / 3;
    const int NP_ = in_sizes[3] / 4;
    const int NI  = in_sizes[4] / 4;

    float* out   = (float*)d_out;
    float* out_a = out;
    float* out_b = out_a + (size_t)N   * 2;
    float* out_g = out_b + (size_t)NB  * 2;
    float* out_p = out_g + (size_t)NAg * 2;
    float* out_i = out_p + (size_t)NP_ * 6;

    // ---- workspace layout (bf16 elements) ----
    unsigned short* nodeb = (unsigned short*)d_ws;
    size_t off = (size_t)N * 128;
    unsigned short* packA = nodeb + off; off += (size_t)128 * 128;
    unsigned short* packB = nodeb + off; off += (size_t)256 * 128;
    unsigned short* packG = nodeb + off; off += (size_t)384 * 128;
    unsigned short* packP = nodeb + off; off += (size_t)512 * 128;
    unsigned short* packI = nodeb + off; off += (size_t)512 * 128;
    unsigned short* pk2A  = nodeb + off; off += 4096;
    unsigned short* pk2B  = nodeb + off; off += 4096;
    unsigned short* pk2G  = nodeb + off; off += 4096;
    unsigned short* pk2P  = nodeb + off; off += 4096;
    unsigned short* pk2I  = nodeb + off; off += 4096;

    // ---- pre-pass ----
    {
        const int n4 = N * 128 / 4;
        conv_node<<<(n4 + PBLK - 1) / PBLK, PBLK, 0, stream>>>(node, nodeb, n4);
    }
    pack_w1<128><<<(128 * 128 + PBLK - 1) / PBLK, PBLK, 0, stream>>>(aw1, packA);
    pack_w1<256><<<(256 * 128 + PBLK - 1) / PBLK, PBLK, 0, stream>>>(bw1, packB);
    pack_w1<384><<<(384 * 128 + PBLK - 1) / PBLK, PBLK, 0, stream>>>(gw1, packG);
    pack_w1<512><<<(512 * 128 + PBLK - 1) / PBLK, PBLK, 0, stream>>>(pw1, packP);
    pack_w1<512><<<(512 * 128 + PBLK - 1) / PBLK, PBLK, 0, stream>>>(iw1, packI);
    pack_w2_all<<<(5 * 4096 + PBLK - 1) / PBLK, PBLK, 0, stream>>>(
        aw2, bw2, gw2, pw2, iw2, pk2A, pk2B, pk2G, pk2P, pk2I);

    // ---- term kernels (persistent grid-stride over 32-row tiles) ----
    const int nt0 = (N   + 31) / 32, g0 = nt0 < 1024 ? nt0 : 1024;
    const int nt1 = (NB  + 31) / 32, g1 = nt1 < 1024 ? nt1 : 1024;
    const int nt2 = (NAg + 31) / 32, g2 = nt2 < 1024 ? nt2 : 1024;
    const int nt3 = (NP_ + 31) / 32, g3 = nt3 <  768 ? nt3 :  768;
    const int nt4 = (NI  + 31) / 32, g4 = nt4 <  512 ? nt4 :  512;

    term_mfma<0, 4><<<g0, 256, 0, stream>>>(nodeb, nullptr, packA, pk2A, ab1, ab2, out_a, N,   nt0);
    term_mfma<1, 4><<<g1, 256, 0, stream>>>(nodeb, bidx,    packB, pk2B, bb1, bb2, out_b, NB,  nt1);
    term_mfma<2, 4><<<g2, 256, 0, stream>>>(nodeb, gidx,    packG, pk2G, gb1, gb2, out_g, NAg, nt2);
    term_mfma<3, 3><<<g3, 256, 0, stream>>>(nodeb, pidx,    packP, pk2P, pb1, pb2, out_p, NP_, nt3);
    term_mfma<4, 2><<<g4, 256, 0, stream>>>(nodeb, iidx,    packI, pk2I, ib1, ib2, out_i, NI,  nt4);
}

// Round 17
// 292.945 us; speedup vs baseline: 1.2725x; 1.2725x over previous
//
#include <hip/hip_runtime.h>

#define PBLK 256

typedef __attribute__((ext_vector_type(8))) short bf16x8;
typedef __attribute__((ext_vector_type(16))) float f32x16;

__device__ __forceinline__ unsigned short f2bf(float x) {
    unsigned int u = __builtin_bit_cast(unsigned int, x);
    u += 0x7fffu + ((u >> 16) & 1u);
    return (unsigned short)(u >> 16);
}

// ---- pre-pass 1: node_reps fp32 -> bf16 ----
__global__ void conv_node(const float* __restrict__ x, unsigned short* __restrict__ o, int n4) {
    int tid = blockIdx.x * PBLK + threadIdx.x;
    if (tid >= n4) return;
    const float4 v = reinterpret_cast<const float4*>(x)[tid];
    ushort4 r;
    r.x = f2bf(v.x); r.y = f2bf(v.y); r.z = f2bf(v.z); r.w = f2bf(v.w);
    reinterpret_cast<ushort4*>(o)[tid] = r;
}

// ---- pre-pass 2: pack w1 (K x 128) into SINGLE-copy 32x32x16 B-frag layout ----
template<int K>
__global__ void pack_w1(const float* __restrict__ w1, unsigned short* __restrict__ o) {
    constexpr int KS = K / 16;
    int tid = blockIdx.x * PBLK + threadIdx.x;
    if (tid >= K * 128) return;
    const int j = tid & 7;
    const int l = (tid >> 3) & 63;
    const int cts = tid >> 9;
    const int s  = cts % KS;
    const int ct = cts / KS;
    const int col = ct * 32 + (l & 31);
    const int k = s * 16 + (l >> 5) * 8 + j;
    o[tid] = f2bf(w1[(size_t)k * 128 + col]);
}

// ---- pre-pass 3: pack all w2 (128 x DOUT) into 32x32x16 B-frag layout ----
__global__ void pack_w2_all(const float* __restrict__ wa, const float* __restrict__ wb,
                            const float* __restrict__ wg, const float* __restrict__ wp,
                            const float* __restrict__ wi,
                            unsigned short* __restrict__ oa, unsigned short* __restrict__ ob,
                            unsigned short* __restrict__ og, unsigned short* __restrict__ op,
                            unsigned short* __restrict__ oi) {
    int tid = blockIdx.x * PBLK + threadIdx.x;
    if (tid >= 5 * 4096) return;
    const int term = tid >> 12, e = tid & 4095;
    const float* w; unsigned short* o; int dout;
    switch (term) {
        case 0: w = wa; o = oa; dout = 2; break;
        case 1: w = wb; o = ob; dout = 2; break;
        case 2: w = wg; o = og; dout = 2; break;
        case 3: w = wp; o = op; dout = 6; break;
        default: w = wi; o = oi; dout = 6; break;
    }
    const int j = e & 7, l = (e >> 3) & 63, s = e >> 9;
    const int col = l & 31;
    const int k = s * 16 + (l >> 5) * 8 + j;
    o[e] = (col < dout) ? f2bf(w[k * dout + col]) : (unsigned short)0;
}

// ---- async global->LDS, 16B per lane ----
__device__ __forceinline__ void gld_lds16(const unsigned short* g, unsigned char* l) {
    typedef __attribute__((address_space(1))) unsigned int GU;
    typedef __attribute__((address_space(3))) unsigned int LU;
    __builtin_amdgcn_global_load_lds((GU*)g, (LU*)l, 16, 0, 0);
}

// forced-wide 16B global load (asm "=v": value live issue->use; asm-volatile
// mutual order preserved -> countable vmcnt ledger)
template<int OFF>
__device__ __forceinline__ void glb16(bf16x8& d, const unsigned short* p) {
    if constexpr (OFF == 0)
        asm volatile("global_load_dwordx4 %0, %1, off" : "=v"(d) : "v"(p));
    else
        asm volatile("global_load_dwordx4 %0, %1, off offset:%2" : "=v"(d) : "v"(p), "i"(OFF));
}

template<int N> __device__ __forceinline__ void waitvm() {
    if constexpr (N == 0)       asm volatile("s_waitcnt vmcnt(0)"  ::: "memory");
    else if constexpr (N == 1)  asm volatile("s_waitcnt vmcnt(1)"  ::: "memory");
    else if constexpr (N == 2)  asm volatile("s_waitcnt vmcnt(2)"  ::: "memory");
    else if constexpr (N == 3)  asm volatile("s_waitcnt vmcnt(3)"  ::: "memory");
    else if constexpr (N == 4)  asm volatile("s_waitcnt vmcnt(4)"  ::: "memory");
    else if constexpr (N == 6)  asm volatile("s_waitcnt vmcnt(6)"  ::: "memory");
    else if constexpr (N == 8)  asm volatile("s_waitcnt vmcnt(8)"  ::: "memory");
    else if constexpr (N == 9)  asm volatile("s_waitcnt vmcnt(9)"  ::: "memory");
    else if constexpr (N == 12) asm volatile("s_waitcnt vmcnt(12)" ::: "memory");
    else                        asm volatile("s_waitcnt vmcnt(0)"  ::: "memory");
}

// ---- per-term config ----
template<int TERM> struct TC;
template<> struct TC<0> { static constexpr int NA = 1, NP = 1, DO = 2;
                          static constexpr int P[1][4] = {{0,0,0,0}}; };
template<> struct TC<1> { static constexpr int NA = 2, NP = 2, DO = 2;
                          static constexpr int P[2][4] = {{0,1,0,0},{1,0,0,0}}; };
template<> struct TC<2> { static constexpr int NA = 3, NP = 2, DO = 2;
                          static constexpr int P[2][4] = {{0,1,2,0},{2,1,0,0}}; };
template<> struct TC<3> { static constexpr int NA = 4, NP = 2, DO = 6;
                          static constexpr int P[2][4] = {{0,1,2,3},{3,2,1,0}}; };
template<> struct TC<4> { static constexpr int NA = 4, NP = 3, DO = 6;
                          static constexpr int P[3][4] = {{0,1,2,3},{2,1,3,0},{3,1,0,2}}; };

// ---- per-term body: EXACTLY the proven r12 structure ----
// Persistent grid-stride over 32-row tiles, 4 waves (ct 0..3), wave tile
// 32 rows x 32 cols, mfma_f32_32x32x16_bf16, streaming-B pure asm-load
// vmcnt ledger; G gather issued in epilogue when FIFO is empty, flies
// across raw barrier B, drained before barrier C.
template<int TERM>
__device__ __forceinline__ void term_body(
    unsigned char* lds,
    const unsigned short* __restrict__ nodeb,
    const int* __restrict__ idx,
    const unsigned short* __restrict__ pack,
    const unsigned short* __restrict__ pk2,
    const float* __restrict__ b1,
    const float* __restrict__ b2,
    float* __restrict__ out,
    int nrows, int ntiles, int bid0, int GS)
{
    constexpr int NA   = TC<TERM>::NA;
    constexpr int NP   = TC<TERM>::NP;
    constexpr int DOUT = TC<TERM>::DO;
    constexpr int BUF  = NA * 8192;

    const int t    = threadIdx.x;
    const int l    = t & 63;
    const int w    = t >> 6;
    const int l31  = l & 31;
    const int hi   = l >> 5;
    const int l15  = l & 15;
    const int qr   = l >> 4;
    const int rowb = l31;

    const unsigned short* pbp[NA][2];
    #pragma unroll
    for (int b = 0; b < NA; ++b)
        #pragma unroll
        for (int h = 0; h < 2; ++h)
            pbp[b][h] = pack + (((size_t)w * (NA * 8) + b * 8 + h * 4) * 64 + l) * 8;

    const int col = w * 32 + l31;
    const float bv = b1[col];
    const float b2v = (l31 < DOUT) ? b2[l31] * (float)NP : 0.0f;

    int nrw[NA * 2];
    int tile = bid0;

    // ---- prologue: gather tile0 into buf0 ----
    #pragma unroll
    for (int a = 0; a < NA; ++a)
        #pragma unroll
        for (int q = 0; q < 2; ++q) {
            const int rl = w * 8 + q * 4 + qr;
            int gr = tile * 32 + rl; if (gr >= nrows) gr = nrows - 1;
            nrw[a * 2 + q] = idx ? idx[gr * NA + a] : gr;
        }
    #pragma unroll
    for (int a = 0; a < NA; ++a)
        #pragma unroll
        for (int q = 0; q < 2; ++q) {
            const int rl = w * 8 + q * 4 + qr;
            gld_lds16(nodeb + (size_t)nrw[a * 2 + q] * 128 + ((l15 ^ (rl & 15)) << 3),
                      lds + a * 8192 + (w * 8 + q * 4) * 256);
        }
    waitvm<0>();
    __builtin_amdgcn_s_barrier();

    int cur = 0;
    for (; tile < ntiles; tile += GS) {
        const bool hasnext = (tile + GS) < ntiles;
        unsigned char* xb   = lds + cur * BUF;
        unsigned char* obuf = lds + (cur ^ 1) * BUF;

        if (hasnext) {
            #pragma unroll
            for (int a = 0; a < NA; ++a)
                #pragma unroll
                for (int q = 0; q < 2; ++q) {
                    const int rl = w * 8 + q * 4 + qr;
                    int gr = (tile + GS) * 32 + rl; if (gr >= nrows) gr = nrows - 1;
                    nrw[a * 2 + q] = idx ? idx[gr * NA + a] : gr;
                }
        }

        f32x16 acc[NP];
        #pragma unroll
        for (int p = 0; p < NP; ++p)
            #pragma unroll
            for (int i = 0; i < 16; ++i) acc[p][i] = bv;

        bf16x8 Bf[4][NA];
#define ISSUEB(J) do { _Pragma("unroll")                                           \
        for (int b = 0; b < NA; ++b)                                               \
            glb16<((J) & 3) * 1024>(Bf[(J) & 3][b], pbp[b][(J) >> 2]); } while (0)
#define KSTEP(C) do {                                                              \
        waitvm<NA * (((7 - (C)) < 3) ? (7 - (C)) : 3)>();                          \
        __builtin_amdgcn_sched_barrier(0);                                         \
        bf16x8 av[NA];                                                             \
        _Pragma("unroll")                                                          \
        for (int s = 0; s < NA; ++s)                                               \
            av[s] = *reinterpret_cast<const bf16x8*>(                              \
                xb + s * 8192 + rowb * 256 + ((((C) * 2 + hi) ^ (rowb & 15)) << 4)); \
        _Pragma("unroll")                                                          \
        for (int b = 0; b < NA; ++b) {                                             \
            _Pragma("unroll")                                                      \
            for (int p = 0; p < NP; ++p)                                           \
                acc[p] = __builtin_amdgcn_mfma_f32_32x32x16_bf16(                  \
                    av[TC<TERM>::P[p][b]], Bf[(C) & 3][b], acc[p], 0, 0, 0);       \
        }                                                                          \
        if constexpr ((C) + 4 <= 7) ISSUEB((C) + 4);                               \
    } while (0)

        ISSUEB(0); ISSUEB(1); ISSUEB(2); ISSUEB(3);
        KSTEP(0); KSTEP(1); KSTEP(2); KSTEP(3);
        KSTEP(4); KSTEP(5); KSTEP(6); KSTEP(7);
#undef KSTEP
#undef ISSUEB

        __builtin_amdgcn_s_barrier();          // A: all waves done reading xb

        // ---- G: next tile's gather -> obuf (FIFO empty; flies across B) ----
        if (hasnext) {
            #pragma unroll
            for (int a = 0; a < NA; ++a)
                #pragma unroll
                for (int q = 0; q < 2; ++q) {
                    const int rl = w * 8 + q * 4 + qr;
                    gld_lds16(nodeb + (size_t)nrw[a * 2 + q] * 128 + ((l15 ^ (rl & 15)) << 3),
                              obuf + a * 8192 + (w * 8 + q * 4) * 256);
                }
        }

        // ---- h = sum_p relu(acc_p) -> bf16 in xb, A-frag layout ----
        #pragma unroll
        for (int i = 0; i < 16; ++i) {
            const int rowl = (i & 3) + 8 * (i >> 2) + 4 * hi;
            float v = 0.0f;
            #pragma unroll
            for (int p = 0; p < NP; ++p) v += fmaxf(acc[p][i], 0.0f);
            *reinterpret_cast<unsigned short*>(
                xb + rowl * 256 + (((col >> 3) ^ (rowl & 15)) << 4) + (col & 7) * 2) = f2bf(v);
        }
        asm volatile("s_waitcnt lgkmcnt(0)" ::: "memory");
        __builtin_amdgcn_s_barrier();          // B: h visible (G still in flight)

        // ---- layer 2: y = h @ w2 via 8 MFMAs (all waves compute, w0 stores) ----
        {
            f32x16 a2;
            #pragma unroll
            for (int i = 0; i < 16; ++i) a2[i] = 0.0f;
            #pragma unroll
            for (int s = 0; s < 8; ++s) {
                const bf16x8 ah = *reinterpret_cast<const bf16x8*>(
                    xb + rowb * 256 + (((s * 2 + hi) ^ (rowb & 15)) << 4));
                const bf16x8 bw = *reinterpret_cast<const bf16x8*>(pk2 + ((size_t)s * 64 + l) * 8);
                a2 = __builtin_amdgcn_mfma_f32_32x32x16_bf16(ah, bw, a2, 0, 0, 0);
            }
            if (w == 0 && l31 < DOUT) {
                #pragma unroll
                for (int i = 0; i < 16; ++i) {
                    const int rowl = (i & 3) + 8 * (i >> 2) + 4 * hi;
                    const int grow = tile * 32 + rowl;
                    if (grow < nrows) out[(size_t)grow * DOUT + l31] = a2[i] + b2v;
                }
            }
        }
        __builtin_amdgcn_sched_barrier(0);
        waitvm<0>();                           // own G (+ pk2/stores) drained
        __builtin_amdgcn_s_barrier();          // C: obuf ready for all waves
        cur ^= 1;
    }
}

// ---- fused kernel: one launch, blocks binned to terms (block-uniform) ----
struct FArgs {
    const unsigned short* nodeb;
    const int *bidx, *gidx, *pidx, *iidx;
    const unsigned short *packA, *packB, *packG, *packP, *packI;
    const unsigned short *pk2A, *pk2B, *pk2G, *pk2P, *pk2I;
    const float *ab1, *ab2, *bb1, *bb2, *gb1, *gb2, *pb1, *pb2, *ib1, *ib2;
    float *oa, *ob, *og, *op, *oi;
    int N, NB, NG, NP_, NI;
    int ntA, ntB, ntG, ntP, ntI;
    int gA, gB, gG, gP, gI;
};

__global__ __launch_bounds__(256, 2) void fused_terms(FArgs a) {
    __shared__ __align__(16) unsigned char lds[65536];
    int b = blockIdx.x;
    if (b < a.gA) {
        term_body<0>(lds, a.nodeb, nullptr, a.packA, a.pk2A, a.ab1, a.ab2, a.oa, a.N,   a.ntA, b, a.gA);
        return;
    }
    b -= a.gA;
    if (b < a.gB) {
        term_body<1>(lds, a.nodeb, a.bidx,  a.packB, a.pk2B, a.bb1, a.bb2, a.ob, a.NB,  a.ntB, b, a.gB);
        return;
    }
    b -= a.gB;
    if (b < a.gG) {
        term_body<2>(lds, a.nodeb, a.gidx,  a.packG, a.pk2G, a.gb1, a.gb2, a.og, a.NG,  a.ntG, b, a.gG);
        return;
    }
    b -= a.gG;
    if (b < a.gP) {
        term_body<3>(lds, a.nodeb, a.pidx,  a.packP, a.pk2P, a.pb1, a.pb2, a.op, a.NP_, a.ntP, b, a.gP);
        return;
    }
    b -= a.gP;
    term_body<4>(lds, a.nodeb, a.iidx,  a.packI, a.pk2I, a.ib1, a.ib2, a.oi, a.NI,  a.ntI, b, a.gI);
}

extern "C" void kernel_launch(void* const* d_in, const int* in_sizes, int n_in,
                              void* d_out, int out_size, void* d_ws, size_t ws_size,
                              hipStream_t stream) {
    const float* node = (const float*)d_in[0];
    const int* bidx = (const int*)d_in[1];
    const int* gidx = (const int*)d_in[2];
    const int* pidx = (const int*)d_in[3];
    const int* iidx = (const int*)d_in[4];

    const float* aw1 = (const float*)d_in[5];
    const float* ab1 = (const float*)d_in[6];
    const float* aw2 = (const float*)d_in[7];
    const float* ab2 = (const float*)d_in[8];
    const float* bw1 = (const float*)d_in[9];
    const float* bb1 = (const float*)d_in[10];
    const float* bw2 = (const float*)d_in[11];
    const float* bb2 = (const float*)d_in[12];
    const float* gw1 = (const float*)d_in[13];
    const float* gb1 = (const float*)d_in[14];
    const float* gw2 = (const float*)d_in[15];
    const float* gb2 = (const float*)d_in[16];
    const float* pw1 = (const float*)d_in[17];
    const float* pb1 = (const float*)d_in[18];
    const float* pw2 = (const float*)d_in[19];
    const float* pb2 = (const float*)d_in[20];
    const float* iw1 = (const float*)d_in[21];
    const float* ib1 = (const float*)d_in[22];
    const float* iw2 = (const float*)d_in[23];
    const float* ib2 = (const float*)d_in[24];

    const int N   = in_sizes[0] / 128;
    const int NB  = in_sizes[1] / 2;
    const int NG  = in_sizes[2] / 3;
    const int NP_ = in_sizes[3] / 4;
    const int NI  = in_sizes[4] / 4;

    float* out   = (float*)d_out;
    float* out_a = out;
    float* out_b = out_a + (size_t)N   * 2;
    float* out_g = out_b + (size_t)NB  * 2;
    float* out_p = out_g + (size_t)NG  * 2;
    float* out_i = out_p + (size_t)NP_ * 6;

    // ---- workspace layout (bf16 elements) ----
    unsigned short* nodeb = (unsigned short*)d_ws;
    size_t off = (size_t)N * 128;
    unsigned short* packA = nodeb + off; off += (size_t)128 * 128;
    unsigned short* packB = nodeb + off; off += (size_t)256 * 128;
    unsigned short* packG = nodeb + off; off += (size_t)384 * 128;
    unsigned short* packP = nodeb + off; off += (size_t)512 * 128;
    unsigned short* packI = nodeb + off; off += (size_t)512 * 128;
    unsigned short* pk2A  = nodeb + off; off += 4096;
    unsigned short* pk2B  = nodeb + off; off += 4096;
    unsigned short* pk2G  = nodeb + off; off += 4096;
    unsigned short* pk2P  = nodeb + off; off += 4096;
    unsigned short* pk2I  = nodeb + off; off += 4096;

    // ---- pre-pass ----
    {
        const int n4 = N * 128 / 4;
        conv_node<<<(n4 + PBLK - 1) / PBLK, PBLK, 0, stream>>>(node, nodeb, n4);
    }
    pack_w1<128><<<(128 * 128 + PBLK - 1) / PBLK, PBLK, 0, stream>>>(aw1, packA);
    pack_w1<256><<<(256 * 128 + PBLK - 1) / PBLK, PBLK, 0, stream>>>(bw1, packB);
    pack_w1<384><<<(384 * 128 + PBLK - 1) / PBLK, PBLK, 0, stream>>>(gw1, packG);
    pack_w1<512><<<(512 * 128 + PBLK - 1) / PBLK, PBLK, 0, stream>>>(pw1, packP);
    pack_w1<512><<<(512 * 128 + PBLK - 1) / PBLK, PBLK, 0, stream>>>(iw1, packI);
    pack_w2_all<<<(5 * 4096 + PBLK - 1) / PBLK, PBLK, 0, stream>>>(
        aw2, bw2, gw2, pw2, iw2, pk2A, pk2B, pk2G, pk2P, pk2I);

    // ---- fused launch: 512 blocks = 2/CU at 64KB LDS; split proportional to
    // per-term work (tiles x (NA*NP*8 MFMA + fixed overhead)) so all terms
    // finish together and overlap fully ----
    FArgs a;
    a.nodeb = nodeb;
    a.bidx = bidx; a.gidx = gidx; a.pidx = pidx; a.iidx = iidx;
    a.packA = packA; a.packB = packB; a.packG = packG; a.packP = packP; a.packI = packI;
    a.pk2A = pk2A; a.pk2B = pk2B; a.pk2G = pk2G; a.pk2P = pk2P; a.pk2I = pk2I;
    a.ab1 = ab1; a.ab2 = ab2; a.bb1 = bb1; a.bb2 = bb2;
    a.gb1 = gb1; a.gb2 = gb2; a.pb1 = pb1; a.pb2 = pb2; a.ib1 = ib1; a.ib2 = ib2;
    a.oa = out_a; a.ob = out_b; a.og = out_g; a.op = out_p; a.oi = out_i;
    a.N = N; a.NB = NB; a.NG = NG; a.NP_ = NP_; a.NI = NI;
    a.ntA = (N   + 31) / 32;
    a.ntB = (NB  + 31) / 32;
    a.ntG = (NG  + 31) / 32;
    a.ntP = (NP_ + 31) / 32;
    a.ntI = (NI  + 31) / 32;
    a.gA = a.ntA < 28  ? a.ntA : 28;
    a.gB = a.ntB < 68  ? a.ntB : 68;
    a.gG = a.ntG < 148 ? a.ntG : 148;
    a.gP = a.ntP < 228 ? a.ntP : 228;
    a.gI = a.ntI < 40  ? a.ntI : 40;
    const int grid = a.gA + a.gB + a.gG + a.gP + a.gI;

    fused_terms<<<grid, 256, 0, stream>>>(a);
}

// Round 18
// 257.471 us; speedup vs baseline: 1.4478x; 1.1378x over previous
//
#include <hip/hip_runtime.h>

#define PBLK 256

typedef __attribute__((ext_vector_type(8))) short bf16x8;
typedef __attribute__((ext_vector_type(16))) float f32x16;

__device__ __forceinline__ unsigned short f2bf(float x) {
    unsigned int u = __builtin_bit_cast(unsigned int, x);
    u += 0x7fffu + ((u >> 16) & 1u);
    return (unsigned short)(u >> 16);
}

// ---- pre-pass 1: node_reps fp32 -> bf16 ----
__global__ void conv_node(const float* __restrict__ x, unsigned short* __restrict__ o, int n4) {
    int tid = blockIdx.x * PBLK + threadIdx.x;
    if (tid >= n4) return;
    const float4 v = reinterpret_cast<const float4*>(x)[tid];
    ushort4 r;
    r.x = f2bf(v.x); r.y = f2bf(v.y); r.z = f2bf(v.z); r.w = f2bf(v.w);
    reinterpret_cast<ushort4*>(o)[tid] = r;
}

// ---- pre-pass 2: pack w1 (K x 128) into SINGLE-copy 32x32x16 B-frag layout ----
template<int K>
__global__ void pack_w1(const float* __restrict__ w1, unsigned short* __restrict__ o) {
    constexpr int KS = K / 16;
    int tid = blockIdx.x * PBLK + threadIdx.x;
    if (tid >= K * 128) return;
    const int j = tid & 7;
    const int l = (tid >> 3) & 63;
    const int cts = tid >> 9;
    const int s  = cts % KS;
    const int ct = cts / KS;
    const int col = ct * 32 + (l & 31);
    const int k = s * 16 + (l >> 5) * 8 + j;
    o[tid] = f2bf(w1[(size_t)k * 128 + col]);
}

// ---- pre-pass 3: pack all w2 (128 x DOUT) into 32x32x16 B-frag layout ----
__global__ void pack_w2_all(const float* __restrict__ wa, const float* __restrict__ wb,
                            const float* __restrict__ wg, const float* __restrict__ wp,
                            const float* __restrict__ wi,
                            unsigned short* __restrict__ oa, unsigned short* __restrict__ ob,
                            unsigned short* __restrict__ og, unsigned short* __restrict__ op,
                            unsigned short* __restrict__ oi) {
    int tid = blockIdx.x * PBLK + threadIdx.x;
    if (tid >= 5 * 4096) return;
    const int term = tid >> 12, e = tid & 4095;
    const float* w; unsigned short* o; int dout;
    switch (term) {
        case 0: w = wa; o = oa; dout = 2; break;
        case 1: w = wb; o = ob; dout = 2; break;
        case 2: w = wg; o = og; dout = 2; break;
        case 3: w = wp; o = op; dout = 6; break;
        default: w = wi; o = oi; dout = 6; break;
    }
    const int j = e & 7, l = (e >> 3) & 63, s = e >> 9;
    const int col = l & 31;
    const int k = s * 16 + (l >> 5) * 8 + j;
    o[e] = (col < dout) ? f2bf(w[k * dout + col]) : (unsigned short)0;
}

// ---- async global->LDS, 16B per lane ----
__device__ __forceinline__ void gld_lds16(const unsigned short* g, unsigned char* l) {
    typedef __attribute__((address_space(1))) unsigned int GU;
    typedef __attribute__((address_space(3))) unsigned int LU;
    __builtin_amdgcn_global_load_lds((GU*)g, (LU*)l, 16, 0, 0);
}

// forced-wide 16B global load (asm "=v": value live issue->use; asm-volatile
// mutual order preserved -> countable vmcnt ledger)
template<int OFF>
__device__ __forceinline__ void glb16(bf16x8& d, const unsigned short* p) {
    if constexpr (OFF == 0)
        asm volatile("global_load_dwordx4 %0, %1, off" : "=v"(d) : "v"(p));
    else
        asm volatile("global_load_dwordx4 %0, %1, off offset:%2" : "=v"(d) : "v"(p), "i"(OFF));
}

template<int N> __device__ __forceinline__ void waitvm() {
    if constexpr (N == 0)       asm volatile("s_waitcnt vmcnt(0)"  ::: "memory");
    else if constexpr (N == 1)  asm volatile("s_waitcnt vmcnt(1)"  ::: "memory");
    else if constexpr (N == 2)  asm volatile("s_waitcnt vmcnt(2)"  ::: "memory");
    else if constexpr (N == 3)  asm volatile("s_waitcnt vmcnt(3)"  ::: "memory");
    else if constexpr (N == 4)  asm volatile("s_waitcnt vmcnt(4)"  ::: "memory");
    else if constexpr (N == 6)  asm volatile("s_waitcnt vmcnt(6)"  ::: "memory");
    else if constexpr (N == 8)  asm volatile("s_waitcnt vmcnt(8)"  ::: "memory");
    else if constexpr (N == 9)  asm volatile("s_waitcnt vmcnt(9)"  ::: "memory");
    else if constexpr (N == 12) asm volatile("s_waitcnt vmcnt(12)" ::: "memory");
    else                        asm volatile("s_waitcnt vmcnt(0)"  ::: "memory");
}

// ---- per-term config ----
template<int TERM> struct TC;
template<> struct TC<0> { static constexpr int NA = 1, NP = 1, DO = 2;
                          static constexpr int P[1][4] = {{0,0,0,0}}; };
template<> struct TC<1> { static constexpr int NA = 2, NP = 2, DO = 2;
                          static constexpr int P[2][4] = {{0,1,0,0},{1,0,0,0}}; };
template<> struct TC<2> { static constexpr int NA = 3, NP = 2, DO = 2;
                          static constexpr int P[2][4] = {{0,1,2,0},{2,1,0,0}}; };
template<> struct TC<3> { static constexpr int NA = 4, NP = 2, DO = 6;
                          static constexpr int P[2][4] = {{0,1,2,3},{3,2,1,0}}; };
template<> struct TC<4> { static constexpr int NA = 4, NP = 3, DO = 6;
                          static constexpr int P[3][4] = {{0,1,2,3},{2,1,3,0},{3,1,0,2}}; };

// ---- main term kernel: r12 structure + {w0-only layer-2, split a2 chain,
// T5 setprio around MFMA clusters} ----
template<int TERM, int MINW>
__global__ __launch_bounds__(256, MINW) void term_mfma(
    const unsigned short* __restrict__ nodeb,  // (N,128) bf16
    const int* __restrict__ idx,               // (nrows,NA) or nullptr
    const unsigned short* __restrict__ pack,   // K*128 bf16 (single copy)
    const unsigned short* __restrict__ pk2,    // 8*64*8 bf16 packed w2
    const float* __restrict__ b1,              // (128)
    const float* __restrict__ b2,              // (DOUT)
    float* __restrict__ out,                   // (nrows,DOUT)
    int nrows, int ntiles)
{
    constexpr int NA   = TC<TERM>::NA;
    constexpr int NP   = TC<TERM>::NP;
    constexpr int DOUT = TC<TERM>::DO;
    constexpr int BUF  = NA * 8192;            // 32 rows x 256B per slot
    __shared__ __align__(16) unsigned char lds[2 * BUF];

    const int t    = threadIdx.x;
    const int l    = t & 63;
    const int w    = t >> 6;                   // wave id = col tile
    const int l31  = l & 31;
    const int hi   = l >> 5;
    const int l15  = l & 15;
    const int qr   = l >> 4;
    const int rowb = l31;
    const int GS   = gridDim.x;

    const unsigned short* pbp[NA][2];
    #pragma unroll
    for (int b = 0; b < NA; ++b)
        #pragma unroll
        for (int h = 0; h < 2; ++h)
            pbp[b][h] = pack + (((size_t)w * (NA * 8) + b * 8 + h * 4) * 64 + l) * 8;

    const int col = w * 32 + l31;
    const float bv = b1[col];
    const float b2v = (l31 < DOUT) ? b2[l31] * (float)NP : 0.0f;

    int nrw[NA * 2];
    int tile = blockIdx.x;

    // ---- prologue: gather tile0 into buf0 ----
    #pragma unroll
    for (int a = 0; a < NA; ++a)
        #pragma unroll
        for (int q = 0; q < 2; ++q) {
            const int rl = w * 8 + q * 4 + qr;
            int gr = tile * 32 + rl; if (gr >= nrows) gr = nrows - 1;
            nrw[a * 2 + q] = idx ? idx[gr * NA + a] : gr;
        }
    #pragma unroll
    for (int a = 0; a < NA; ++a)
        #pragma unroll
        for (int q = 0; q < 2; ++q) {
            const int rl = w * 8 + q * 4 + qr;
            gld_lds16(nodeb + (size_t)nrw[a * 2 + q] * 128 + ((l15 ^ (rl & 15)) << 3),
                      lds + a * 8192 + (w * 8 + q * 4) * 256);
        }
    waitvm<0>();
    __builtin_amdgcn_s_barrier();

    int cur = 0;
    for (; tile < ntiles; tile += GS) {
        const bool hasnext = (tile + GS) < ntiles;
        unsigned char* xb = lds + cur * BUF;
        unsigned char* ob = lds + (cur ^ 1) * BUF;

        if (hasnext) {
            #pragma unroll
            for (int a = 0; a < NA; ++a)
                #pragma unroll
                for (int q = 0; q < 2; ++q) {
                    const int rl = w * 8 + q * 4 + qr;
                    int gr = (tile + GS) * 32 + rl; if (gr >= nrows) gr = nrows - 1;
                    nrw[a * 2 + q] = idx ? idx[gr * NA + a] : gr;
                }
        }

        f32x16 acc[NP];
        #pragma unroll
        for (int p = 0; p < NP; ++p)
            #pragma unroll
            for (int i = 0; i < 16; ++i) acc[p][i] = bv;

        bf16x8 Bf[4][NA];
#define ISSUEB(J) do { _Pragma("unroll")                                           \
        for (int b = 0; b < NA; ++b)                                               \
            glb16<((J) & 3) * 1024>(Bf[(J) & 3][b], pbp[b][(J) >> 2]); } while (0)

#define KSTEP(C) do {                                                              \
        waitvm<NA * (((7 - (C)) < 3) ? (7 - (C)) : 3)>();                          \
        __builtin_amdgcn_sched_barrier(0);                                         \
        bf16x8 av[NA];                                                             \
        _Pragma("unroll")                                                          \
        for (int s = 0; s < NA; ++s)                                               \
            av[s] = *reinterpret_cast<const bf16x8*>(                              \
                xb + s * 8192 + rowb * 256 + ((((C) * 2 + hi) ^ (rowb & 15)) << 4)); \
        __builtin_amdgcn_s_setprio(1);                                             \
        _Pragma("unroll")                                                          \
        for (int b = 0; b < NA; ++b) {                                             \
            _Pragma("unroll")                                                      \
            for (int p = 0; p < NP; ++p)                                           \
                acc[p] = __builtin_amdgcn_mfma_f32_32x32x16_bf16(                  \
                    av[TC<TERM>::P[p][b]], Bf[(C) & 3][b], acc[p], 0, 0, 0);       \
        }                                                                          \
        __builtin_amdgcn_s_setprio(0);                                             \
        if constexpr ((C) + 4 <= 7) ISSUEB((C) + 4);                               \
    } while (0)

        ISSUEB(0); ISSUEB(1); ISSUEB(2); ISSUEB(3);
        KSTEP(0); KSTEP(1); KSTEP(2); KSTEP(3);
        KSTEP(4); KSTEP(5); KSTEP(6); KSTEP(7);
#undef KSTEP
#undef ISSUEB

        __builtin_amdgcn_s_barrier();          // A: all waves done reading xb

        // ---- G: next tile's gather -> ob (FIFO empty; flies across B) ----
        if (hasnext) {
            #pragma unroll
            for (int a = 0; a < NA; ++a)
                #pragma unroll
                for (int q = 0; q < 2; ++q) {
                    const int rl = w * 8 + q * 4 + qr;
                    gld_lds16(nodeb + (size_t)nrw[a * 2 + q] * 128 + ((l15 ^ (rl & 15)) << 3),
                              ob + a * 8192 + (w * 8 + q * 4) * 256);
                }
        }

        // ---- h = sum_p relu(acc_p) -> bf16 in xb, A-frag layout ----
        #pragma unroll
        for (int i = 0; i < 16; ++i) {
            const int rowl = (i & 3) + 8 * (i >> 2) + 4 * hi;
            float v = 0.0f;
            #pragma unroll
            for (int p = 0; p < NP; ++p) v += fmaxf(acc[p][i], 0.0f);
            *reinterpret_cast<unsigned short*>(
                xb + rowl * 256 + (((col >> 3) ^ (rowl & 15)) << 4) + (col & 7) * 2) = f2bf(v);
        }
        asm volatile("s_waitcnt lgkmcnt(0)" ::: "memory");
        __builtin_amdgcn_s_barrier();          // B: h visible (G still in flight)

        // ---- layer 2: w0 ONLY (was redundantly computed by all 4 waves).
        // Frees 24 ds_read_b128 + 24 MFMA/tile from the pipes gating barrier C.
        // a2 split into 2 chains to halve the serial MFMA dep latency.
        if (w == 0) {
            __builtin_amdgcn_s_setprio(1);
            f32x16 a2e, a2o;
            #pragma unroll
            for (int i = 0; i < 16; ++i) { a2e[i] = 0.0f; a2o[i] = 0.0f; }
            #pragma unroll
            for (int s = 0; s < 8; s += 2) {
                const bf16x8 ah0 = *reinterpret_cast<const bf16x8*>(
                    xb + rowb * 256 + (((s * 2 + hi) ^ (rowb & 15)) << 4));
                const bf16x8 ah1 = *reinterpret_cast<const bf16x8*>(
                    xb + rowb * 256 + ((((s + 1) * 2 + hi) ^ (rowb & 15)) << 4));
                const bf16x8 bw0 = *reinterpret_cast<const bf16x8*>(pk2 + ((size_t)s * 64 + l) * 8);
                const bf16x8 bw1 = *reinterpret_cast<const bf16x8*>(pk2 + ((size_t)(s + 1) * 64 + l) * 8);
                a2e = __builtin_amdgcn_mfma_f32_32x32x16_bf16(ah0, bw0, a2e, 0, 0, 0);
                a2o = __builtin_amdgcn_mfma_f32_32x32x16_bf16(ah1, bw1, a2o, 0, 0, 0);
            }
            __builtin_amdgcn_s_setprio(0);
            if (l31 < DOUT) {
                #pragma unroll
                for (int i = 0; i < 16; ++i) {
                    const int rowl = (i & 3) + 8 * (i >> 2) + 4 * hi;
                    const int grow = tile * 32 + rowl;
                    if (grow < nrows) out[(size_t)grow * DOUT + l31] = a2e[i] + a2o[i] + b2v;
                }
            }
        }
        __builtin_amdgcn_sched_barrier(0);
        waitvm<0>();                           // own G (+ pk2/stores) drained
        __builtin_amdgcn_s_barrier();          // C: ob ready for all waves
        cur ^= 1;
    }
}

extern "C" void kernel_launch(void* const* d_in, const int* in_sizes, int n_in,
                              void* d_out, int out_size, void* d_ws, size_t ws_size,
                              hipStream_t stream) {
    const float* node = (const float*)d_in[0];
    const int* bidx = (const int*)d_in[1];
    const int* gidx = (const int*)d_in[2];
    const int* pidx = (const int*)d_in[3];
    const int* iidx = (const int*)d_in[4];

    const float* aw1 = (const float*)d_in[5];
    const float* ab1 = (const float*)d_in[6];
    const float* aw2 = (const float*)d_in[7];
    const float* ab2 = (const float*)d_in[8];
    const float* bw1 = (const float*)d_in[9];
    const float* bb1 = (const float*)d_in[10];
    const float* bw2 = (const float*)d_in[11];
    const float* bb2 = (const float*)d_in[12];
    const float* gw1 = (const float*)d_in[13];
    const float* gb1 = (const float*)d_in[14];
    const float* gw2 = (const float*)d_in[15];
    const float* gb2 = (const float*)d_in[16];
    const float* pw1 = (const float*)d_in[17];
    const float* pb1 = (const float*)d_in[18];
    const float* pw2 = (const float*)d_in[19];
    const float* pb2 = (const float*)d_in[20];
    const float* iw1 = (const float*)d_in[21];
    const float* ib1 = (const float*)d_in[22];
    const float* iw2 = (const float*)d_in[23];
    const float* ib2 = (const float*)d_in[24];

    const int N   = in_sizes[0] / 128;
    const int NB  = in_sizes[1] / 2;
    const int NAg = in_sizes[2] / 3;
    const int NP_ = in_sizes[3] / 4;
    const int NI  = in_sizes[4] / 4;

    float* out   = (float*)d_out;
    float* out_a = out;
    float* out_b = out_a + (size_t)N   * 2;
    float* out_g = out_b + (size_t)NB  * 2;
    float* out_p = out_g + (size_t)NAg * 2;
    float* out_i = out_p + (size_t)NP_ * 6;

    // ---- workspace layout (bf16 elements) ----
    unsigned short* nodeb = (unsigned short*)d_ws;
    size_t off = (size_t)N * 128;
    unsigned short* packA = nodeb + off; off += (size_t)128 * 128;
    unsigned short* packB = nodeb + off; off += (size_t)256 * 128;
    unsigned short* packG = nodeb + off; off += (size_t)384 * 128;
    unsigned short* packP = nodeb + off; off += (size_t)512 * 128;
    unsigned short* packI = nodeb + off; off += (size_t)512 * 128;
    unsigned short* pk2A  = nodeb + off; off += 4096;
    unsigned short* pk2B  = nodeb + off; off += 4096;
    unsigned short* pk2G  = nodeb + off; off += 4096;
    unsigned short* pk2P  = nodeb + off; off += 4096;
    unsigned short* pk2I  = nodeb + off; off += 4096;

    // ---- pre-pass ----
    {
        const int n4 = N * 128 / 4;
        conv_node<<<(n4 + PBLK - 1) / PBLK, PBLK, 0, stream>>>(node, nodeb, n4);
    }
    pack_w1<128><<<(128 * 128 + PBLK - 1) / PBLK, PBLK, 0, stream>>>(aw1, packA);
    pack_w1<256><<<(256 * 128 + PBLK - 1) / PBLK, PBLK, 0, stream>>>(bw1, packB);
    pack_w1<384><<<(384 * 128 + PBLK - 1) / PBLK, PBLK, 0, stream>>>(gw1, packG);
    pack_w1<512><<<(512 * 128 + PBLK - 1) / PBLK, PBLK, 0, stream>>>(pw1, packP);
    pack_w1<512><<<(512 * 128 + PBLK - 1) / PBLK, PBLK, 0, stream>>>(iw1, packI);
    pack_w2_all<<<(5 * 4096 + PBLK - 1) / PBLK, PBLK, 0, stream>>>(
        aw2, bw2, gw2, pw2, iw2, pk2A, pk2B, pk2G, pk2P, pk2I);

    // ---- term kernels (persistent grid-stride over 32-row tiles) ----
    const int nt0 = (N   + 31) / 32, g0 = nt0 < 1024 ? nt0 : 1024;
    const int nt1 = (NB  + 31) / 32, g1 = nt1 < 1280 ? nt1 : 1280;
    const int nt2 = (NAg + 31) / 32, g2 = nt2 <  768 ? nt2 :  768;
    const int nt3 = (NP_ + 31) / 32, g3 = nt3 <  512 ? nt3 :  512;
    const int nt4 = (NI  + 31) / 32, g4 = nt4 <  512 ? nt4 :  512;

    term_mfma<0, 2><<<g0, 256, 0, stream>>>(nodeb, nullptr, packA, pk2A, ab1, ab2, out_a, N,   nt0);
    term_mfma<1, 2><<<g1, 256, 0, stream>>>(nodeb, bidx,    packB, pk2B, bb1, bb2, out_b, NB,  nt1);
    term_mfma<2, 2><<<g2, 256, 0, stream>>>(nodeb, gidx,    packG, pk2G, gb1, gb2, out_g, NAg, nt2);
    term_mfma<3, 2><<<g3, 256, 0, stream>>>(nodeb, pidx,    packP, pk2P, pb1, pb2, out_p, NP_, nt3);
    term_mfma<4, 2><<<g4, 256, 0, stream>>>(nodeb, iidx,    packI, pk2I, ib1, ib2, out_i, NI,  nt4);
}